// Round 14
// baseline (741.350 us; speedup 1.0000x reference)
//
#include <hip/hip_runtime.h>
#include <hip/hip_fp16.h>
#include <cmath>

#define NN 200000
#define EE 6400000
#define CSH 8             // bucket = col >> 8 (256 nodes/bucket)  [r12-proven geometry]
#define BSZ 256           // nodes per bucket
#define NBKT 782          // ceil(200000 / 256)
#define GRID_A 512        // blocks in phase-A kernels (MUST match scan width)
#define BLK_A 256
#define RB_SHIFT 13       // row band = row >> 13 (8192 rows/band)  [r10/r12-proven]
#define NRB 25            // ceil(200000 / 8192)

// ---- fp16 helpers: inter-layer y buffers are PACKED half2 words ----
// max over fp16 pairs via v_pk_max_f16 (handles signs/-0 correctly, no monotone
// encoding needed). LDS accumulator updated with guarded CAS (monotone -> terminates,
// result = elementwise max -> order-invariant/deterministic).
__device__ __forceinline__ unsigned int pkmax_f16(unsigned int a, unsigned int b) {
    unsigned int r;
    asm("v_pk_max_f16 %0, %1, %2" : "=v"(r) : "v"(a), "v"(b));
    return r;
}
__device__ __forceinline__ void lds_max_f16(unsigned int* addr, unsigned int v) {
    unsigned int cur = *addr;                  // guard read (broadcasts for same-lc lanes)
    unsigned int mx = pkmax_f16(cur, v);
    while (mx != cur) {                        // only improving lanes touch the atomic
        unsigned int old = atomicCAS(addr, cur, mx);
        if (old == cur) break;
        cur = old;
        mx = pkmax_f16(cur, v);
    }
}
__device__ __forceinline__ float f16tof32(unsigned short s) {
    union { unsigned short u; __half h; } cv; cv.u = s;
    return __half2float(cv.h);
}
__device__ __forceinline__ float f16lo(unsigned int w) { return f16tof32((unsigned short)(w & 0xFFFFu)); }
__device__ __forceinline__ float f16hi(unsigned int w) { return f16tof32((unsigned short)(w >> 16)); }
__device__ __forceinline__ unsigned int pack16(float a, float b) {
    union { __half2 h2; unsigned int u; } cv;
    cv.h2 = __floats2half2_rn(a, b);
    return cv.u;
}

// row loader: YW = padded u32-words per node row (16B-aligned strides where vectorized)
template<int YW>
__device__ __forceinline__ void loadrow(const unsigned int* __restrict__ y, size_t r,
                                        unsigned int* cw) {
    if constexpr (YW == 12) {
        const uint4* p = (const uint4*)(y + r * 12);
        uint4 a = p[0], b = p[1], c = p[2];
        cw[0]=a.x; cw[1]=a.y; cw[2]=a.z; cw[3]=a.w;
        cw[4]=b.x; cw[5]=b.y; cw[6]=b.z; cw[7]=b.w;
        cw[8]=c.x; cw[9]=c.y; cw[10]=c.z; cw[11]=c.w;
    } else if constexpr (YW == 8) {
        const uint4* p = (const uint4*)(y + r * 8);
        uint4 a = p[0], b = p[1];
        cw[0]=a.x; cw[1]=a.y; cw[2]=a.z; cw[3]=a.w;
        cw[4]=b.x; cw[5]=b.y; cw[6]=b.z; cw[7]=b.w;
    } else if constexpr (YW == 4) {
        uint4 a = *(const uint4*)(y + r * 4);
        cw[0]=a.x; cw[1]=a.y; cw[2]=a.z; cw[3]=a.w;
    } else if constexpr (YW == 2) {
        uint2 a = *(const uint2*)(y + r * 2);
        cw[0]=a.x; cw[1]=a.y;
    } else {
        cw[0] = y[r];
    }
}

// =============== Phase A: bucket edges by col>>CSH (counting sort, LDS atomics only) ===============

__global__ __launch_bounds__(BLK_A) void count_buckets_kernel(const int* __restrict__ col,
                                                              int* __restrict__ blkhist) {
    __shared__ int h[NBKT];
    for (int t = threadIdx.x; t < NBKT; t += BLK_A) h[t] = 0;
    __syncthreads();
    const int4* col4 = (const int4*)col;
    for (int i = blockIdx.x * BLK_A + threadIdx.x; i < EE / 4; i += GRID_A * BLK_A) {
        int4 c = col4[i];
        atomicAdd(&h[c.x >> CSH], 1);
        atomicAdd(&h[c.y >> CSH], 1);
        atomicAdd(&h[c.z >> CSH], 1);
        atomicAdd(&h[c.w >> CSH], 1);
    }
    __syncthreads();
    for (int t = threadIdx.x; t < NBKT; t += BLK_A) blkhist[blockIdx.x * NBKT + t] = h[t];
}

__global__ __launch_bounds__(GRID_A) void scan_cols_kernel(int* __restrict__ blkhist,
                                                           int* __restrict__ btot) {
    __shared__ int sc[GRID_A];
    int bkt = blockIdx.x, t = threadIdx.x;
    int v = blkhist[t * NBKT + bkt];
    sc[t] = v;
    __syncthreads();
    for (int off = 1; off < GRID_A; off <<= 1) {
        int add = (t >= off) ? sc[t - off] : 0;
        __syncthreads();
        sc[t] += add;
        __syncthreads();
    }
    blkhist[t * NBKT + bkt] = sc[t] - v;  // exclusive along blocks
    if (t == GRID_A - 1) btot[bkt] = sc[t];
}

__global__ __launch_bounds__(1024) void scan_btot_kernel(const int* __restrict__ btot,
                                                         int* __restrict__ bbase) {
    __shared__ int sc[1024];
    int t = threadIdx.x;
    int v = (t < NBKT) ? btot[t] : 0;
    sc[t] = v;
    __syncthreads();
    for (int off = 1; off < 1024; off <<= 1) {
        int add = (t >= off) ? sc[t - off] : 0;
        __syncthreads();
        sc[t] += add;
        __syncthreads();
    }
    if (t < NBKT) bbase[t] = sc[t] - v;
    if (t == NBKT - 1) bbase[NBKT] = sc[t];  // total = EE
}

// A3: place packed codes (int4 edge loads). code = (col&255)<<18 | row  (row < 2^18)
__global__ __launch_bounds__(BLK_A) void place_pairs_kernel(const int* __restrict__ row,
                                                            const int* __restrict__ col,
                                                            const int* __restrict__ blkhist,
                                                            const int* __restrict__ bbase,
                                                            unsigned int* __restrict__ pairs) {
    __shared__ int cur[NBKT];
    for (int t = threadIdx.x; t < NBKT; t += BLK_A)
        cur[t] = bbase[t] + blkhist[blockIdx.x * NBKT + t];
    __syncthreads();
    const int4* col4 = (const int4*)col;
    const int4* row4 = (const int4*)row;
    for (int i = blockIdx.x * BLK_A + threadIdx.x; i < EE / 4; i += GRID_A * BLK_A) {
        int4 c = col4[i];
        int4 r = row4[i];
        int p0 = atomicAdd(&cur[c.x >> CSH], 1);
        pairs[p0] = (unsigned int)r.x | ((unsigned int)(c.x & (BSZ - 1)) << 18);
        int p1 = atomicAdd(&cur[c.y >> CSH], 1);
        pairs[p1] = (unsigned int)r.y | ((unsigned int)(c.y & (BSZ - 1)) << 18);
        int p2 = atomicAdd(&cur[c.z >> CSH], 1);
        pairs[p2] = (unsigned int)r.z | ((unsigned int)(c.z & (BSZ - 1)) << 18);
        int p3 = atomicAdd(&cur[c.w >> CSH], 1);
        pairs[p3] = (unsigned int)r.w | ((unsigned int)(c.w & (BSZ - 1)) << 18);
    }
}

// A4: per-bucket counting sort into BAND-MAJOR order (band = row>>RB_SHIFT).
__global__ __launch_bounds__(512) void bucket_build_band_kernel(const unsigned int* __restrict__ pairs,
                                                                const int* __restrict__ bbase,
                                                                float* __restrict__ dinv,
                                                                unsigned int* __restrict__ codes,
                                                                int* __restrict__ bandoffs) {
    __shared__ int bin[BSZ * NRB];   // 6400: flat band-major, linear n = bb*BSZ + lc
    __shared__ int sc[512];
    int b = blockIdx.x, tid = threadIdx.x;
    int base = bbase[b], end = bbase[b + 1];
    int node0 = b << CSH;
    int nloc = NN - node0; if (nloc > BSZ) nloc = BSZ;

    for (int t = tid; t < BSZ * NRB; t += 512) bin[t] = 0;
    __syncthreads();
    for (int i = base + tid; i < end; i += 512) {
        unsigned int p = pairs[i];
        int lc = p >> 18;
        int rw = (int)(p & 0x3FFFFu);
        atomicAdd(&bin[(rw >> RB_SHIFT) * BSZ + lc], 1);
    }
    __syncthreads();

    // degree -> dinv (read before positions overwrite bins)
    if (tid < nloc) {
        int d = 0;
#pragma unroll
        for (int bb = 0; bb < NRB; ++bb) d += bin[bb * BSZ + tid];
        dinv[node0 + tid] = rsqrtf((float)(d + 1));  // +1 self loop
    }
    __syncthreads();

    // exclusive scan of the flat 6400 array: thread t<BSZ owns chunk [t*NRB, t*NRB+NRB)
    int tot = 0;
    if (tid < BSZ) {
#pragma unroll
        for (int i = 0; i < NRB; ++i) tot += bin[tid * NRB + i];
    }
    sc[tid] = tot;
    __syncthreads();
    for (int off = 1; off < 512; off <<= 1) {
        int add = (tid >= off) ? sc[tid - off] : 0;
        __syncthreads();
        sc[tid] += add;
        __syncthreads();
    }
    if (tid < BSZ) {
        int run = base + sc[tid] - tot;   // global exclusive base of this chunk
#pragma unroll
        for (int i = 0; i < NRB; ++i) {
            int c = bin[tid * NRB + i];
            bin[tid * NRB + i] = run;     // becomes placement cursor
            run += c;
        }
    }
    __syncthreads();

    if (tid < NRB) bandoffs[b * (NRB + 1) + tid] = bin[tid * BSZ];
    if (tid == 0) bandoffs[b * (NRB + 1) + NRB] = end;
    __syncthreads();

    for (int i = base + tid; i < end; i += 512) {
        unsigned int p = pairs[i];
        int lc = p >> 18;
        int rw = (int)(p & 0x3FFFFu);
        int pos = atomicAdd(&bin[(rw >> RB_SHIFT) * BSZ + lc], 1);
        codes[pos] = p;
    }
}

// ====== layer-1 matmul, epilogue premultiplies dinv and PACKS fp16: y1 = half2(dinv*(x@W)) ======
__global__ void matmul128_y_kernel(const float* __restrict__ x, const float* __restrict__ W,
                                   const float* __restrict__ dinv, unsigned int* __restrict__ y, int n) {
    __shared__ float Ws[128 * 24];
    for (int t = threadIdx.x; t < 128 * 24; t += blockDim.x) Ws[t] = W[t];
    __syncthreads();
    int i = blockIdx.x * blockDim.x + threadIdx.x;
    if (i >= n) return;
    float acc[24];
#pragma unroll
    for (int j = 0; j < 24; ++j) acc[j] = 0.f;
    const float4* hr = (const float4*)(x + (size_t)i * 128);
#pragma unroll 8
    for (int k4 = 0; k4 < 32; ++k4) {
        float4 hv = hr[k4];
        const float* wk = &Ws[k4 * 4 * 24];
#pragma unroll
        for (int j = 0; j < 24; ++j) acc[j] += hv.x * wk[j];
#pragma unroll
        for (int j = 0; j < 24; ++j) acc[j] += hv.y * wk[24 + j];
#pragma unroll
        for (int j = 0; j < 24; ++j) acc[j] += hv.z * wk[48 + j];
#pragma unroll
        for (int j = 0; j < 24; ++j) acc[j] += hv.w * wk[72 + j];
    }
    float di = dinv[i];
    uint4 o0, o1, o2;
    o0.x = pack16(di * acc[0],  di * acc[1]);
    o0.y = pack16(di * acc[2],  di * acc[3]);
    o0.z = pack16(di * acc[4],  di * acc[5]);
    o0.w = pack16(di * acc[6],  di * acc[7]);
    o1.x = pack16(di * acc[8],  di * acc[9]);
    o1.y = pack16(di * acc[10], di * acc[11]);
    o1.z = pack16(di * acc[12], di * acc[13]);
    o1.w = pack16(di * acc[14], di * acc[15]);
    o2.x = pack16(di * acc[16], di * acc[17]);
    o2.y = pack16(di * acc[18], di * acc[19]);
    o2.z = pack16(di * acc[20], di * acc[21]);
    o2.w = pack16(di * acc[22], di * acc[23]);
    uint4* orow = (uint4*)(y + (size_t)i * 12);
    orow[0] = o0; orow[1] = o1; orow[2] = o2;
}

// =============== band-phased bucket gather on PACKED-fp16 y: v_pk_max_f16 + guarded CAS ==============
// 256-node buckets, 782 blocks x 512 threads (r12-proven locality geometry).
// Per edge: 1 code load + YWI/4-ish row loads (half the bytes and HALF the TA
// addresses of the f32 version) + NW guarded pk_max updates (half the LDS ops).
// PHASES template: NRB band phases for big y (L2 lockstep sweep); PHASES=1 when
// y fits per-XCD L2 (y4, y5). Phase-2 epilogue is per-thread (no h staging ->
// LDS ~15.6KB). Odd LDS stride keeps random-lc access spread over all banks.
template<int DOUT, int DNEXT, int YWI, int YWO, bool FINAL, int PHASES>
__global__ __launch_bounds__(512) void gather_band_kernel(const unsigned int* __restrict__ codes,
                                                          const int* __restrict__ bandoffs,
                                                          const float* __restrict__ dinv,
                                                          const unsigned int* __restrict__ y,   // fp16-packed
                                                          const float* __restrict__ bias,
                                                          const float* __restrict__ Wn,
                                                          const float* __restrict__ bcls,
                                                          unsigned int* __restrict__ outp,      // fp16-packed
                                                          float* __restrict__ fout,
                                                          float* __restrict__ hout) {
    constexpr int NW = DOUT / 2;           // half2 words per node
    constexpr int ST = NW | 1;             // odd stride -> conflict-free random access
    __shared__ unsigned int acc[BSZ * ST];
    __shared__ float dcs[BSZ];
    __shared__ float Ws[DOUT * DNEXT];
    __shared__ float bs[DOUT];
    const int b0 = blockIdx.x;
    const int node0 = b0 << CSH;
    const int nloc = (NN - node0 < BSZ) ? (NN - node0) : BSZ;
    const int tid = threadIdx.x;

    if (tid < DOUT * DNEXT) Ws[tid] = Wn[tid];
    if (tid < DOUT) bs[tid] = bias[tid];
    if (tid < nloc) dcs[tid] = dinv[node0 + tid];
    for (int idx = tid; idx < nloc * NW; idx += 512) {
        int lc = idx / NW;
        int w  = idx - lc * NW;
        acc[lc * ST + w] = y[(size_t)(node0 + lc) * YWI + w];   // self-loop seed
    }
    __syncthreads();

    const int* bo = bandoffs + b0 * (NRB + 1);
#pragma unroll 1
    for (int ph = 0; ph < PHASES; ++ph) {
        const int s0 = (PHASES == 1) ? bo[0] : bo[ph];
        const int e  = (PHASES == 1) ? bo[NRB] : bo[ph + 1];
        for (int i = s0 + tid; i < e; i += 1024) {
            const int i2 = i + 512;
            const bool two = (i2 < e);
            unsigned int p0 = codes[i];
            size_t r0 = (size_t)(p0 & 0x3FFFFu);
            unsigned int* a0 = &acc[(p0 >> 18) * ST];
            unsigned int cw0[YWI], cw1[YWI];
            loadrow<YWI>(y, r0, cw0);
            unsigned int* a1 = nullptr;
            if (two) {
                unsigned int p1 = codes[i2];
                loadrow<YWI>(y, (size_t)(p1 & 0x3FFFFu), cw1);
                a1 = &acc[(p1 >> 18) * ST];
            }
#pragma unroll
            for (int w = 0; w < NW; ++w) lds_max_f16(&a0[w], cw0[w]);
            if (two) {
#pragma unroll
                for (int w = 0; w < NW; ++w) lds_max_f16(&a1[w], cw1[w]);
            }
        }
        __syncthreads();   // band phase barrier (once total when PHASES==1)
    }

    // phase 2 (per-thread, thread tid owns node node0+tid): decode fp16 max,
    // tanh in f32, next-layer matmul in f32, pack fp16 out (or classifier).
    if (tid < nloc) {
        const int node = node0 + tid;
        float dc = dcs[tid];
        float h[DOUT];
#pragma unroll
        for (int w = 0; w < NW; ++w) {
            unsigned int u = acc[tid * ST + w];
            h[2 * w]     = f16lo(u);
            h[2 * w + 1] = f16hi(u);
        }
#pragma unroll
        for (int f = 0; f < DOUT; ++f) h[f] = tanhf(dc * h[f] + bs[f]);
        if constexpr (!FINAL) {
            constexpr int NWO = DNEXT / 2;
#pragma unroll
            for (int jw = 0; jw < NWO; ++jw) {
                float o0 = 0.f, o1 = 0.f;
#pragma unroll
                for (int k = 0; k < DOUT; ++k) {
                    o0 += h[k] * Ws[k * DNEXT + 2 * jw];
                    o1 += h[k] * Ws[k * DNEXT + 2 * jw + 1];
                }
                outp[(size_t)node * YWO + jw] = pack16(dc * o0, dc * o1);
            }
        } else {
            float2 ho; ho.x = h[0]; ho.y = h[1];
            ((float2*)hout)[node] = ho;
            float4 o;
            o.x = h[0] * Ws[0] + h[1] * Ws[DNEXT + 0] + bcls[0];
            o.y = h[0] * Ws[1] + h[1] * Ws[DNEXT + 1] + bcls[1];
            o.z = h[0] * Ws[2] + h[1] * Ws[DNEXT + 2] + bcls[2];
            o.w = h[0] * Ws[3] + h[1] * Ws[DNEXT + 3] + bcls[3];
            ((float4*)fout)[node] = o;
        }
    }
}

extern "C" void kernel_launch(void* const* d_in, const int* in_sizes, int n_in,
                              void* d_out, int out_size, void* d_ws, size_t ws_size,
                              hipStream_t stream) {
    const float* x  = (const float*)d_in[0];
    const int*   ei = (const int*)d_in[1];
    const int* row = ei;            // edge_index[0] = source
    const int* col = ei + EE;       // edge_index[1] = target
    const float* W1 = (const float*)d_in[2];  const float* b1 = (const float*)d_in[3];
    const float* W2 = (const float*)d_in[4];  const float* b2 = (const float*)d_in[5];
    const float* W3 = (const float*)d_in[6];  const float* b3 = (const float*)d_in[7];
    const float* W4 = (const float*)d_in[8];  const float* b4 = (const float*)d_in[9];
    const float* W5 = (const float*)d_in[10]; const float* b5 = (const float*)d_in[11];
    const float* Wc = (const float*)d_in[12]; const float* bc = (const float*)d_in[13];
    float* out = (float*)d_out;

    // ---- workspace carve (same offsets as r12; fp16 y buffers are smaller) ----
    // y word-strides (u32/node): y1=12 (9.6MB), y2=8 (6.4MB), y3=4 (3.2MB), y4=2 (1.6MB), y5=1 (0.8MB)
    // pairs is dead before matmul128_y writes bufB -> alias them. codes persists all layers.
    char* ws = (char*)d_ws;
    float*        dinv       = (float*)(ws + 0);                //    800,000
    int*          bandoffs   = (int*)(ws + 800000);             //     81,328 (NBKT*(NRB+1)) -> pad 81,408
    int*          bbase      = (int*)(ws + 881408);             //      3,132 -> pad 3,200
    int*          btot       = (int*)(ws + 884608);             //      3,128 -> pad 3,200
    int*          blkhist    = (int*)(ws + 887808);             //  1,601,536 (GRID_A*NBKT ints)
    unsigned int* codes      = (unsigned int*)(ws + 2489344);   // 25,600,000
    unsigned int* pairs      = (unsigned int*)(ws + 28089344);  // 25,600,000
    unsigned int* bufB       = (unsigned int*)(ws + 28089344);  // (aliases pairs; y1/y3/y5 fp16-packed)
    unsigned int* bufA       = (unsigned int*)(ws + 53689344);  //  6,400,000 (y2/y4 fp16-packed)
    // total: 60,089,344 B

    const int BLK = 256;
    const int gN = (NN + BLK - 1) / BLK;       // 782

    // ---- CSR build: two-level counting sort; adjacency emitted band-major per bucket ----
    count_buckets_kernel<<<GRID_A, BLK_A, 0, stream>>>(col, blkhist);
    scan_cols_kernel<<<NBKT, GRID_A, 0, stream>>>(blkhist, btot);
    scan_btot_kernel<<<1, 1024, 0, stream>>>(btot, bbase);
    place_pairs_kernel<<<GRID_A, BLK_A, 0, stream>>>(row, col, blkhist, bbase, pairs);
    bucket_build_band_kernel<<<NBKT, 512, 0, stream>>>(pairs, bbase, dinv, codes, bandoffs);

    // ---- layer 1 matmul: y1 = half2(dinv * (x @ W1)), [N,24] fp16-packed ----
    matmul128_y_kernel<<<gN, BLK, 0, stream>>>(x, W1, dinv, bufB, NN);

    // ---- layer 1 gather + layer-2 matmul fused: y2 (banded; y1 9.6MB) ----
    gather_band_kernel<24, 12, 12, 8, false, NRB><<<NBKT, 512, 0, stream>>>(
        codes, bandoffs, dinv, bufB, b1, W2, nullptr, bufA, nullptr, nullptr);
    // ---- layer 2 gather + layer-3 matmul fused: y3 (banded; y2 6.4MB) ----
    gather_band_kernel<12, 6, 8, 4, false, NRB><<<NBKT, 512, 0, stream>>>(
        codes, bandoffs, dinv, bufA, b2, W3, nullptr, bufB, nullptr, nullptr);
    // ---- layer 3 gather + layer-4 matmul fused: y4 (banded; y3 3.2MB) ----
    gather_band_kernel<6, 4, 4, 2, false, NRB><<<NBKT, 512, 0, stream>>>(
        codes, bandoffs, dinv, bufB, b3, W4, nullptr, bufA, nullptr, nullptr);
    // ---- layer 4 gather + layer-5 matmul fused: y5 (single-phase; y4 1.6MB L2-fit) ----
    gather_band_kernel<4, 2, 2, 1, false, 1><<<NBKT, 512, 0, stream>>>(
        codes, bandoffs, dinv, bufA, b4, W5, nullptr, bufB, nullptr, nullptr);
    // ---- layer 5 gather + classifier fused: out [N,4], h [N,2] f32 (single-phase; y5 0.8MB) ----
    gather_band_kernel<2, 4, 1, 1, true, 1><<<NBKT, 512, 0, stream>>>(
        codes, bandoffs, dinv, bufB, b5, Wc, bc, nullptr, out, out + (size_t)NN * 4);
}